// Round 1
// baseline (176.178 us; speedup 1.0000x reference)
//
#include <hip/hip_runtime.h>

// Problem constants (fixed by setup_inputs): B=8, C=64, O=64, H=128, W=128,
// stride=1, padding=1, kernel 3x3.
constexpr int Bc = 8;
constexpr int Cc = 64;
constexpr int Oc = 64;
constexpr int Hc = 128;
constexpr int Wc = 128;
constexpr int HWc = Hc * Wc;

// One block per (b, h) row. 256 threads = 2 channel-halves x 128 w.
// Phase 1: compute agg (periphery-weighted sum of 8 neighbor taps) into LDS,
//          accumulate div partials in registers.
// Phase 2: mask[w] = ((div - thr) * scale) > 0  (== sigmoid(..)>0.5);
//          sel[c][w] = mask ? agg : center  (center reloaded from global,
//          branch is exec-masked away when all lanes have mask=true).
// Phase 3: out[o][w] = sum_c core[o][c] * sel[c][w]; weight index is
//          wave-uniform -> scalar loads; sel held in 64 VGPRs per thread.
__global__ __launch_bounds__(256) void spconv_kernel(
    const float* __restrict__ x, const float* __restrict__ core,
    const float* __restrict__ peri, const float* __restrict__ thr,
    const float* __restrict__ scl, float* __restrict__ out)
{
    __shared__ float s_sel[Cc][Wc];      // 32 KB: agg, then selected vector
    __shared__ float s_divp[2][Wc];      // div partials per channel-half
    __shared__ unsigned s_mask[Wc];

    const int tid  = threadIdx.x;
    const int w    = tid & (Wc - 1);
    const int half = tid >> 7;           // 0 or 1
    const int b    = blockIdx.x >> 7;
    const int h    = blockIdx.x & (Hc - 1);

    const float p0 = peri[0], p1 = peri[1], p2 = peri[2], p3 = peri[3];
    const float p4 = peri[4], p5 = peri[5], p6 = peri[6], p7 = peri[7];

    // Base of row h for channel 0 of this batch image.
    const float* xb = x + (size_t)b * Cc * HWc + (size_t)h * Wc;

    const bool hm = (h > 0), hp = (h < Hc - 1);
    const bool wm = (w > 0), wp = (w < Wc - 1);

    float divacc = 0.f;

    for (int ci = 0; ci < Cc / 2; ++ci) {
        const int c = half * (Cc / 2) + ci;
        const float* row = xb + (size_t)c * HWc;

        const float t4 = row[w];                                   // center
        const float t0 = (hm && wm) ? row[w - Wc - 1] : 0.f;
        const float t1 =  hm        ? row[w - Wc]     : 0.f;
        const float t2 = (hm && wp) ? row[w - Wc + 1] : 0.f;
        const float t3 =  wm        ? row[w - 1]      : 0.f;
        const float t5 =  wp        ? row[w + 1]      : 0.f;
        const float t6 = (hp && wm) ? row[w + Wc - 1] : 0.f;
        const float t7 =  hp        ? row[w + Wc]     : 0.f;
        const float t8 = (hp && wp) ? row[w + Wc + 1] : 0.f;

        // PERI_IDX = [0,1,2,3,5,6,7,8]
        float agg = p0 * t0;
        agg = fmaf(p1, t1, agg);
        agg = fmaf(p2, t2, agg);
        agg = fmaf(p3, t3, agg);
        agg = fmaf(p4, t5, agg);
        agg = fmaf(p5, t6, agg);
        agg = fmaf(p6, t7, agg);
        agg = fmaf(p7, t8, agg);
        s_sel[c][w] = agg;

        const float d0 = t0 - t4, d1 = t1 - t4, d2 = t2 - t4, d3 = t3 - t4;
        const float d5 = t5 - t4, d6 = t6 - t4, d7 = t7 - t4, d8 = t8 - t4;
        divacc = fmaf(d0, d0, divacc);
        divacc = fmaf(d1, d1, divacc);
        divacc = fmaf(d2, d2, divacc);
        divacc = fmaf(d3, d3, divacc);
        divacc = fmaf(d5, d5, divacc);
        divacc = fmaf(d6, d6, divacc);
        divacc = fmaf(d7, d7, divacc);
        divacc = fmaf(d8, d8, divacc);
    }
    s_divp[half][w] = divacc;
    __syncthreads();

    if (tid < Wc) {
        const float div = s_divp[0][tid] + s_divp[1][tid];
        s_mask[tid] = ((div - thr[0]) * scl[0]) > 0.f ? 1u : 0u;
    }
    __syncthreads();

    // sel = mask ? agg : center. Overwrite only where mask == 0 (rare path:
    // with this data div >> thr, so the branch body is usually exec-skipped).
    #pragma unroll
    for (int k = 0; k < (Cc * Wc) / 256; ++k) {
        const int idx = k * 256 + tid;
        const int c  = idx >> 7;
        const int ww = idx & (Wc - 1);
        if (!s_mask[ww]) {
            s_sel[c][ww] = xb[(size_t)c * HWc + ww];   // center = x[b,c,h,ww]
        }
    }
    __syncthreads();

    // Phase 3: matvec. Each thread: fixed w, 32 consecutive o values.
    float r[Cc];
    #pragma unroll
    for (int c = 0; c < Cc; ++c) r[c] = s_sel[c][w];

    const int og = half * (Oc / 2);
    float* outp = out + ((size_t)(b * Oc + og) * Hc + h) * Wc + w;

    for (int oi = 0; oi < Oc / 2; ++oi) {
        const float* wv = core + (size_t)(og + oi) * Cc;  // wave-uniform addr
        float acc = 0.f;
        #pragma unroll
        for (int c = 0; c < Cc; ++c) acc = fmaf(wv[c], r[c], acc);
        outp[(size_t)oi * HWc] = acc;
    }
}

extern "C" void kernel_launch(void* const* d_in, const int* in_sizes, int n_in,
                              void* d_out, int out_size, void* d_ws, size_t ws_size,
                              hipStream_t stream) {
    const float* x    = (const float*)d_in[0];
    const float* core = (const float*)d_in[1];
    const float* peri = (const float*)d_in[2];
    const float* thr  = (const float*)d_in[3];
    const float* scl  = (const float*)d_in[4];
    float* out = (float*)d_out;

    spconv_kernel<<<dim3(Bc * Hc), dim3(256), 0, stream>>>(
        x, core, peri, thr, scl, out);
}

// Round 2
// 106.559 us; speedup vs baseline: 1.6533x; 1.6533x over previous
//
#include <hip/hip_runtime.h>
#include <hip/hip_bf16.h>

// B=8, C=64, O=64, H=W=128, stride=1, pad=1, 3x3.
constexpr int Bc = 8;
constexpr int Cc = 64;
constexpr int Oc = 64;
constexpr int Hc = 128;
constexpr int Wc = 128;
constexpr int HWc = Hc * Wc;
constexpr int CP = 72;   // padded LDS row stride in bf16 elems (144 B: 16B-aligned, bank-stride 4)

typedef __attribute__((ext_vector_type(8))) short short8;   // 8 x bf16 (4 VGPRs)
typedef __attribute__((ext_vector_type(4))) float floatx4;

// One block per (b,h) row, 512 threads = 8 waves.
// Phase 0: stage core (64x64) into LDS as bf16.
// Phase 1: q=tid>>7 selects a 16-channel quarter; each thread computes agg
//          (pre-masked periphery weights -> unconditional clamped loads) into
//          s_selT[w][c] (bf16, transposed for MFMA B-fragments), div partials
//          to s_divp.
// Phase 2: mask[w] = ((div-thr)*scale) > 0  (== sigmoid>0.5); where mask==0
//          overwrite s_selT[w][c] with center (rare path, exec-masked away).
// Phase 3: out[64 o][128 w] = core(64x64) x sel(64x128) via
//          mfma_f32_16x16x32_bf16; 8 waves x 4 tiles x 2 K-steps.
__global__ __launch_bounds__(512) void spconv_kernel(
    const float* __restrict__ x, const float* __restrict__ core,
    const float* __restrict__ peri, const float* __restrict__ thr,
    const float* __restrict__ scl, float* __restrict__ out)
{
    __shared__ __hip_bfloat16 s_selT[Wc][CP];   // [w][c] 18432 B
    __shared__ __hip_bfloat16 s_core[Oc][CP];   // [o][c]  9216 B
    __shared__ float s_divp[4][Wc];             //          2048 B
    __shared__ float s_msk[Wc];                 //           512 B

    const int tid = threadIdx.x;
    const int w   = tid & (Wc - 1);
    const int q   = tid >> 7;                   // channel quarter 0..3
    const int b   = blockIdx.x >> 7;
    const int h   = blockIdx.x & (Hc - 1);

    // ---- Phase 0: core -> bf16 LDS (4096 elems / 512 thr = 8 each) ----
    #pragma unroll
    for (int i = 0; i < 8; ++i) {
        const int idx = i * 512 + tid;
        s_core[idx >> 6][idx & 63] = __float2bfloat16(core[idx]);
    }

    // ---- Phase 1: taps ----
    const float* xb = x + (size_t)b * Cc * HWc + (size_t)h * Wc;

    // PERI_IDX taps: [0,1,2,3,5,6,7,8] -> (dh,dw)
    const int   dh[8] = {-1,-1,-1, 0, 0, 1, 1, 1};
    const int   dw[8] = {-1, 0, 1,-1, 1,-1, 0, 1};
    int   off[8];
    float pl[8], mf[8];
    #pragma unroll
    for (int k = 0; k < 8; ++k) {
        const bool okh = (h + dh[k] >= 0) && (h + dh[k] < Hc);
        const bool okw = (w + dw[k] >= 0) && (w + dw[k] < Wc);
        const bool ok  = okh && okw;
        off[k] = ok ? (w + dh[k] * Wc + dw[k]) : w;   // clamp to a safe addr
        mf[k]  = ok ? 1.f : 0.f;
        pl[k]  = ok ? peri[k] : 0.f;                  // pre-masked weight
    }

    float divacc = 0.f;
    const float* rowq = xb + (size_t)(q * 16) * HWc;
    #pragma unroll 4
    for (int ci = 0; ci < 16; ++ci) {
        const float* row = rowq + (size_t)ci * HWc;
        const float t4 = row[w];
        float v[8];
        #pragma unroll
        for (int k = 0; k < 8; ++k) v[k] = row[off[k]];
        float agg = 0.f;
        #pragma unroll
        for (int k = 0; k < 8; ++k) agg = fmaf(pl[k], v[k], agg);
        s_selT[w][q * 16 + ci] = __float2bfloat16(agg);
        #pragma unroll
        for (int k = 0; k < 8; ++k) {
            const float d = fmaf(mf[k], v[k], -t4);   // padded tap: 0 - center
            divacc = fmaf(d, d, divacc);
        }
    }
    s_divp[q][w] = divacc;
    __syncthreads();

    // ---- Phase 2: mask + sel fixup ----
    if (tid < Wc) {
        const float div = s_divp[0][tid] + s_divp[1][tid]
                        + s_divp[2][tid] + s_divp[3][tid];
        s_msk[tid] = (((div - thr[0]) * scl[0]) > 0.f) ? 1.f : 0.f;
    }
    __syncthreads();

    #pragma unroll
    for (int i = 0; i < 16; ++i) {                // 8192 elems / 512 thr
        const int idx = i * 512 + tid;
        const int ww  = idx & (Wc - 1);
        const int c   = idx >> 7;
        if (s_msk[ww] == 0.f)                     // rare: div >> thr usually
            s_selT[ww][c] = __float2bfloat16(xb[(size_t)c * HWc + ww]);
    }
    __syncthreads();

    // ---- Phase 3: MFMA GEMM: D[o][w] = core[o][c] * sel[c][w], K=64 ----
    const int lane = tid & 63;
    const int wid  = tid >> 6;          // 0..7
    const int o0   = (wid & 3) * 16;    // o-tile
    const int wh   = wid >> 2;          // w-half 0/1 -> 4 w-tiles each
    const int n    = lane & 15;         // col within tile (w), also A-row (o)
    const int quad = lane >> 4;

    // A-fragment: A[m=lane&15][k=quad*8+j], contiguous 8 bf16 -> b128 loads
    const short8 a0 = *(const short8*)&s_core[o0 + n][quad * 8];
    const short8 a1 = *(const short8*)&s_core[o0 + n][quad * 8 + 32];

    float* outb = out + ((size_t)(b * Oc) * Hc + h) * Wc;

    #pragma unroll
    for (int t = 0; t < 4; ++t) {
        const int w0 = (wh * 4 + t) * 16;
        // B-fragment: B[k=quad*8+j][n=lane&15]  (s_selT is [w][c] = B^T rows)
        const short8 b0 = *(const short8*)&s_selT[w0 + n][quad * 8];
        const short8 b1 = *(const short8*)&s_selT[w0 + n][quad * 8 + 32];
        floatx4 acc = {0.f, 0.f, 0.f, 0.f};
        acc = __builtin_amdgcn_mfma_f32_16x16x32_bf16(a0, b0, acc, 0, 0, 0);
        acc = __builtin_amdgcn_mfma_f32_16x16x32_bf16(a1, b1, acc, 0, 0, 0);
        // D: col = lane&15 (w), row = quad*4 + r (o)
        #pragma unroll
        for (int r = 0; r < 4; ++r) {
            const int o = o0 + quad * 4 + r;
            outb[(size_t)o * HWc + w0 + n] = acc[r];
        }
    }
}

extern "C" void kernel_launch(void* const* d_in, const int* in_sizes, int n_in,
                              void* d_out, int out_size, void* d_ws, size_t ws_size,
                              hipStream_t stream) {
    const float* x    = (const float*)d_in[0];
    const float* core = (const float*)d_in[1];
    const float* peri = (const float*)d_in[2];
    const float* thr  = (const float*)d_in[3];
    const float* scl  = (const float*)d_in[4];
    float* out = (float*)d_out;

    spconv_kernel<<<dim3(Bc * Hc), dim3(512), 0, stream>>>(
        x, core, peri, thr, scl, out);
}